// Round 1
// baseline (680.230 us; speedup 1.0000x reference)
//
#include <hip/hip_runtime.h>

// out[n,d] = ci[n] * sum_{e: dst[e]==n} sigmoid(<review_feat[e,:], ps_w>) * cj[src[e]] * weight[src[e], d]
//
// Strategy: single fused edge-parallel kernel.
//   - 1 wave (64 lanes) processes 4 edges.
//   - Dot phase: 16 lanes per edge, float4 loads (16B/lane), shfl_xor reduce.
//   - Scatter phase: all 64 lanes handle one edge's 64-float row at a time:
//     coalesced weight-row gather (L2-resident) + 64 HW f32 atomics into out.
//   - ci[dst] is folded into the per-edge scalar (distributes over the sum),
//     so no epilogue pass is needed.

__device__ __forceinline__ float group16_reduce(float x) {
    // xor offsets < 16 keep the butterfly within each 16-lane group
    x += __shfl_xor(x, 1);
    x += __shfl_xor(x, 2);
    x += __shfl_xor(x, 4);
    x += __shfl_xor(x, 8);
    return x;
}

__global__ __launch_bounds__(256) void gcmc_edge_kernel(
    const float* __restrict__ weight,       // [N,64]
    const float* __restrict__ ps_w,         // [64]
    const float* __restrict__ review_feat,  // [E,64]
    const float* __restrict__ cj,           // [N]
    const float* __restrict__ ci,           // [N]
    const int*   __restrict__ src,          // [E]
    const int*   __restrict__ dst,          // [E]
    float*       __restrict__ out,          // [N,64], pre-zeroed
    int E)
{
    const int lane  = threadIdx.x & 63;
    const int wib   = threadIdx.x >> 6;                      // wave in block
    const int wave  = blockIdx.x * (blockDim.x >> 6) + wib;  // global wave id
    const int group = lane >> 4;   // 0..3 : which of this wave's 4 edges
    const int sub   = lane & 15;   // 0..15: float4 chunk within the 64-row

    const int e4 = wave * 4;       // first edge of this wave
    if (e4 >= E) return;

    // ---- gate: dot(review_feat[e,:], ps_w) over 16 lanes ----
    const int e = e4 + group;
    float x = 0.f;
    if (e < E) {
        const float4 rv = *reinterpret_cast<const float4*>(review_feat + (long long)e * 64 + sub * 4);
        const float4 pw = *reinterpret_cast<const float4*>(ps_w + sub * 4);
        x = rv.x * pw.x + rv.y * pw.y + rv.z * pw.z + rv.w * pw.w;
    }
    x = group16_reduce(x);

    // per-edge scalar: sigmoid(x) * cj[src] * ci[dst]  (ci folded in)
    float scale = 0.f;
    int s = 0, d = 0;
    if (e < E) {
        s = src[e];
        d = dst[e];
        const float gate = 1.f / (1.f + __expf(-x));
        scale = gate * cj[s] * ci[d];
    }

    // ---- scatter: 64 lanes cooperate on one edge row at a time ----
    #pragma unroll
    for (int k = 0; k < 4; ++k) {
        const int sl = k * 16;
        const float sc = __shfl(scale, sl);
        const int   ss = __shfl(s, sl);
        const int   dd = __shfl(d, sl);
        if (e4 + k < E) {
            const float w = weight[(long long)ss * 64 + lane];
            unsafeAtomicAdd(&out[(long long)dd * 64 + lane], sc * w);
        }
    }
}

extern "C" void kernel_launch(void* const* d_in, const int* in_sizes, int n_in,
                              void* d_out, int out_size, void* d_ws, size_t ws_size,
                              hipStream_t stream) {
    const float* weight      = (const float*)d_in[0];
    const float* ps_w        = (const float*)d_in[1];
    const float* review_feat = (const float*)d_in[2];
    const float* cj          = (const float*)d_in[3];
    const float* ci          = (const float*)d_in[4];
    const int*   src         = (const int*)d_in[5];
    const int*   dst         = (const int*)d_in[6];
    float*       out         = (float*)d_out;

    const int E = in_sizes[5];

    // output is accumulated via atomics -> must start from zero every call
    hipMemsetAsync(out, 0, (size_t)out_size * sizeof(float), stream);

    const int waves  = (E + 3) / 4;        // 4 edges per wave
    const int blocks = (waves + 3) / 4;    // 4 waves per 256-thread block
    gcmc_edge_kernel<<<blocks, 256, 0, stream>>>(
        weight, ps_w, review_feat, cj, ci, src, dst, out, E);
}